// Round 1
// baseline (9.798 us; speedup 1.0000x reference)
//
#include <hip/hip_runtime.h>

// The reference network ends with jax.nn.log_softmax(h, axis=1) where h has
// shape [NRES*NRES, 1]. A log_softmax over a size-1 axis is identically zero
// (x - logsumexp(x) == x - x, computed as 0 exactly by the max-shift form for
// any finite x). Every preceding op (both GNNs, neighbor aggregation, the FC
// stack) is dead code. The correct output is exactly zeros(90000) in fp32.

__global__ void zero_fill_f4(float4* __restrict__ out, int n4) {
    int i = blockIdx.x * blockDim.x + threadIdx.x;
    if (i < n4) out[i] = make_float4(0.f, 0.f, 0.f, 0.f);
}

__global__ void zero_fill_tail(float* __restrict__ out, int start, int n) {
    int i = start + blockIdx.x * blockDim.x + threadIdx.x;
    if (i < n) out[i] = 0.f;
}

extern "C" void kernel_launch(void* const* d_in, const int* in_sizes, int n_in,
                              void* d_out, int out_size, void* d_ws, size_t ws_size,
                              hipStream_t stream) {
    (void)d_in; (void)in_sizes; (void)n_in; (void)d_ws; (void)ws_size;

    float* out = (float*)d_out;
    int n  = out_size;      // 90000 (NRES*NRES)
    int n4 = n >> 2;        // float4 chunks (hipMalloc gives >=256B alignment)
    int rem_start = n4 << 2;

    if (n4 > 0) {
        int threads = 256;
        int blocks  = (n4 + threads - 1) / threads;
        zero_fill_f4<<<blocks, threads, 0, stream>>>((float4*)out, n4);
    }
    if (rem_start < n) {
        int rem = n - rem_start;
        zero_fill_tail<<<(rem + 63) / 64, 64, 0, stream>>>(out, rem_start, n);
    }
}